// Round 10
// baseline (222.590 us; speedup 1.0000x reference)
//
#include <hip/hip_runtime.h>
#include <cstdint>
#include <cstddef>

#define L_SEQ 2048
#define E_DIM 512
#define WIN 64
#define SCALE_QK 0.044194173824159216f  // 1/sqrt(512)

#define NBLK 512
#define NTHR 256

typedef __attribute__((ext_vector_type(8))) short short8;
typedef __attribute__((ext_vector_type(4))) float floatx4;

__device__ __forceinline__ unsigned short f2bf(float f) {
    unsigned int u = __float_as_uint(f);
    u += 0x7FFFu + ((u >> 16) & 1u);
    return (unsigned short)(u >> 16);
}

// software grid barrier, FIXED (R9 lesson): poll with RELAXED agent-scope
// loads — on gfx950 an ACQUIRE agent-scope load invalidates the XCD's whole
// (non-coherent) L2, and 512 pollers at ~5 MHz wiped every worker's cache:
// R9's 143 us all-idle stall.  Relaxed scoped atomics bypass the stale caches
// for the polled line only, invalidating nothing.  ONE acquire fence after
// loop exit provides the ordering.  Spin bounded: failure => wrong answer
// (diagnosable), not a hang.
__device__ __forceinline__ void gbar(unsigned int* cnt, unsigned int target) {
    __syncthreads();
    if (threadIdx.x == 0) {
        __threadfence();   // release: write back this block's stores
        __hip_atomic_fetch_add(cnt, 1u, __ATOMIC_RELEASE, __HIP_MEMORY_SCOPE_AGENT);
        unsigned int v = __hip_atomic_load(cnt, __ATOMIC_RELAXED, __HIP_MEMORY_SCOPE_AGENT);
        for (int it = 0; it < 8000000 && v < target; ++it) {
            __builtin_amdgcn_s_sleep(4);
            v = __hip_atomic_load(cnt, __ATOMIC_RELAXED, __HIP_MEMORY_SCOPE_AGENT);
        }
        __threadfence();   // single acquire AFTER exit: invalidate stale lines once
    }
    __syncthreads();
}

// ============================================================================
// ONE kernel, 512 blocks x 256 threads, plain launch.  Phases: A cvt -> gbar
// -> B qkv (bf16 z-loop) -> gbar -> C attn (4-wave (Qt,b,eh) jobs).
// Identical to R9 (which was CORRECT) except the gbar poll semantics.
// ============================================================================
#define ALD 72    // qkv LDS row stride (bf16)
#define SLD 164   // attn S-tile row stride (fp32)
__global__ __launch_bounds__(256, 2) void mega(
    const float* __restrict__ x,
    const float* __restrict__ Wq, const float* __restrict__ bq,
    const float* __restrict__ Wk, const float* __restrict__ bk,
    const float* __restrict__ Wv, const float* __restrict__ bv,
    float* __restrict__ out,
    unsigned short* __restrict__ xb, unsigned short* __restrict__ wb,
    unsigned short* __restrict__ qb, unsigned short* __restrict__ kb,
    unsigned short* __restrict__ vt, unsigned int* __restrict__ cnt)
{
    __shared__ __align__(16) char lds_raw[36864];

    const int t   = threadIdx.x;
    const int bid = blockIdx.x;

    // ===================== Phase A: fp32 -> bf16 (grid-stride) =================
    for (long i = (long)bid * NTHR + t; i < 720896; i += (long)NBLK * NTHR) {
        const float* src; unsigned short* dst; long off;
        if (i < 524288) {
            src = x; dst = xb; off = i;
        } else {
            long j = i - 524288;
            int wsel = (int)(j >> 16);
            off = j & 65535;
            src = (wsel == 0) ? Wq : ((wsel == 1) ? Wk : Wv);
            dst = wb + (long)wsel * 262144;
        }
        float4 f = ((const float4*)src)[off];
        ushort4 o;
        o.x = f2bf(f.x); o.y = f2bf(f.y); o.z = f2bf(f.z); o.w = f2bf(f.w);
        ((ushort4*)dst)[off] = o;
    }
    gbar(cnt, NBLK);

    // ===================== Phase B: QKV projection (bf16, z-loop) ==============
    {
        const int mt = bid & 63, nt = bid >> 6;
        const int m0 = mt * 64, n0 = nt * 64;

        unsigned short* As = (unsigned short*)lds_raw;          // [64][ALD]
        unsigned short* Bs = As + 64 * ALD;                     // [3][64][ALD]

        const int w = t >> 6, l = t & 63;
        const int wm = (w >> 1) * 32, wn = (w & 1) * 32;
        const int fr = l & 15, fq = l >> 4, fk = fq * 8;

        const int srow = t >> 2, scol = (t & 3) * 16;
        const unsigned short* gA = xb + (size_t)(m0 + srow) * 512 + scol;
        const unsigned short* gB = wb + (size_t)(n0 + srow) * 512 + scol;

        float bv_[3][2];
        {
            const float* bs[3] = { bq, bk, bv };
#pragma unroll
            for (int z = 0; z < 3; z++)
#pragma unroll
                for (int j = 0; j < 2; j++) bv_[z][j] = bs[z][n0 + wn + j * 16 + fr];
        }

        floatx4 acc[3][2][2] = {};

        for (int kt = 0; kt < 8; kt++) {
            const int kk = kt * 64;
            *(uint4*)&As[srow * ALD + scol]     = *(const uint4*)(gA + kk);
            *(uint4*)&As[srow * ALD + scol + 8] = *(const uint4*)(gA + kk + 8);
#pragma unroll
            for (int z = 0; z < 3; z++) {
                *(uint4*)&Bs[z * 64 * ALD + srow * ALD + scol]     = *(const uint4*)(gB + (size_t)z * 262144 + kk);
                *(uint4*)&Bs[z * 64 * ALD + srow * ALD + scol + 8] = *(const uint4*)(gB + (size_t)z * 262144 + kk + 8);
            }
            __syncthreads();

            short8 a[2][2];
#pragma unroll
            for (int i = 0; i < 2; i++)
#pragma unroll
                for (int kh = 0; kh < 2; kh++)
                    a[i][kh] = *(const short8*)&As[(wm + i * 16 + fr) * ALD + kh * 32 + fk];
#pragma unroll
            for (int z = 0; z < 3; z++) {
                short8 bf[2][2];
#pragma unroll
                for (int j = 0; j < 2; j++)
#pragma unroll
                    for (int kh = 0; kh < 2; kh++)
                        bf[j][kh] = *(const short8*)&Bs[z * 64 * ALD + (wn + j * 16 + fr) * ALD + kh * 32 + fk];
#pragma unroll
                for (int kh = 0; kh < 2; kh++)
#pragma unroll
                    for (int i = 0; i < 2; i++)
#pragma unroll
                        for (int j = 0; j < 2; j++)
                            acc[z][i][j] = __builtin_amdgcn_mfma_f32_16x16x32_bf16(a[i][kh], bf[j][kh], acc[z][i][j], 0, 0, 0);
            }
            __syncthreads();
        }

        // epilogue per z through LDS transpose tile (alias As)
        unsigned short* Tl = As;
        const int tr = t >> 2, tc = (t & 3) * 16;
#pragma unroll
        for (int z = 0; z < 3; z++) {
            if (z) __syncthreads();
            if (z < 2) {
#pragma unroll
                for (int i = 0; i < 2; i++)
#pragma unroll
                    for (int j = 0; j < 2; j++)
#pragma unroll
                        for (int r = 0; r < 4; r++)
                            Tl[(wm + i * 16 + fq * 4 + r) * ALD + wn + j * 16 + fr] =
                                f2bf(acc[z][i][j][r] + bv_[z][j]);
            } else {
#pragma unroll
                for (int i = 0; i < 2; i++)
#pragma unroll
                    for (int j = 0; j < 2; j++)
#pragma unroll
                        for (int r = 0; r < 4; r++)
                            Tl[(wn + j * 16 + fr) * ALD + wm + i * 16 + fq * 4 + r] =
                                f2bf(acc[z][i][j][r] + bv_[z][j]);
            }
            __syncthreads();

            uint4 v0 = *(const uint4*)&Tl[tr * ALD + tc];
            uint4 v1 = *(const uint4*)&Tl[tr * ALD + tc + 8];
            if (z < 2) {
                unsigned short* o = (z == 0) ? qb : kb;
                size_t off = (size_t)(m0 + tr) * 512 + n0 + tc;
                *(uint4*)&o[off]     = v0;
                *(uint4*)&o[off + 8] = v1;
            } else {
                size_t off = (size_t)(n0 + tr) * 4096 + m0 + tc;
                *(uint4*)&vt[off]     = v0;
                *(uint4*)&vt[off + 8] = v1;
            }
        }
    }
    gbar(cnt, 2 * NBLK);

    // ===================== Phase C: fused attention, 512 (Qt,b,eh) jobs ========
    {
        float* Sl = (float*)lds_raw;   // 16 x SLD fp32

        const int g   = bid >> 3, xcd = bid & 7;
        const int Qt  = xcd * 16 + (g & 15);
        const int eh  = (g >> 4) & 1;
        const int b   = g >> 5;
        const int w = t >> 6, l = t & 63;
        const int fr = l & 15, fq = l >> 4;
        const int Q0 = Qt * 16;
        const int R0 = Q0 - WIN;

        // ---- scores
        {
            const unsigned short* qrow = qb + (size_t)(b * L_SEQ + Q0 + fr) * 512 + fq * 8;
            short8 qf[16];
#pragma unroll
            for (int ks = 0; ks < 16; ks++) qf[ks] = *(const short8*)(qrow + ks * 32);

            for (int nt = w; nt < 9; nt += 4) {
                const int tok = R0 + nt * 16 + fr;
                const bool kvalid = (tok >= 0) && (tok < L_SEQ);
                const int tokc = min(max(tok, 0), L_SEQ - 1);
                const unsigned short* krow = kb + (size_t)(b * L_SEQ + tokc) * 512 + fq * 8;

                floatx4 acc0 = {}, acc1 = {};
                short8 bfr[8];
#pragma unroll
                for (int ks = 0; ks < 8; ks++) bfr[ks] = *(const short8*)(krow + ks * 32);
#pragma unroll
                for (int ks = 0; ks < 8; ks++)
                    acc0 = __builtin_amdgcn_mfma_f32_16x16x32_bf16(qf[ks], bfr[ks], acc0, 0, 0, 0);
#pragma unroll
                for (int ks = 0; ks < 8; ks++) bfr[ks] = *(const short8*)(krow + (8 + ks) * 32);
#pragma unroll
                for (int ks = 0; ks < 8; ks++)
                    acc1 = __builtin_amdgcn_mfma_f32_16x16x32_bf16(qf[8 + ks], bfr[ks], acc1, 0, 0, 0);

                const int jg = nt * 16 + fr;
#pragma unroll
                for (int r = 0; r < 4; r++) {
                    int qq = fq * 4 + r;
                    bool valid = kvalid && (jg >= qq) && (jg <= qq + 128);
                    Sl[qq * SLD + jg] = valid ? (acc0[r] + acc1[r]) * SCALE_QK : -1e30f;
                }
            }
        }
        __syncthreads();

        // ---- softmax (per-wave redundant)
        const float* Srow = &Sl[fr * SLD + fq * 8];
        float sv[5][8];
#pragma unroll
        for (int ks = 0; ks < 5; ks++) {
            float4 u0 = *(const float4*)(Srow + ks * 32);
            float4 u1 = *(const float4*)(Srow + ks * 32 + 4);
            sv[ks][0] = u0.x; sv[ks][1] = u0.y; sv[ks][2] = u0.z; sv[ks][3] = u0.w;
            sv[ks][4] = u1.x; sv[ks][5] = u1.y; sv[ks][6] = u1.z; sv[ks][7] = u1.w;
        }
        if (fq >= 2) {
#pragma unroll
            for (int j = 0; j < 8; j++) sv[4][j] = -1e30f;
        }
        float m = -1e30f;
#pragma unroll
        for (int ks = 0; ks < 5; ks++)
#pragma unroll
            for (int j = 0; j < 8; j++) m = fmaxf(m, sv[ks][j]);
        m = fmaxf(m, __shfl_xor(m, 16));
        m = fmaxf(m, __shfl_xor(m, 32));
        float sum = 0.f;
#pragma unroll
        for (int ks = 0; ks < 5; ks++)
#pragma unroll
            for (int j = 0; j < 8; j++) { float e = __expf(sv[ks][j] - m); sv[ks][j] = e; sum += e; }
        sum += __shfl_xor(sum, 16);
        sum += __shfl_xor(sum, 32);
        float inv = 1.f / sum;

        short8 a[5];
#pragma unroll
        for (int ks = 0; ks < 5; ks++)
#pragma unroll
            for (int j = 0; j < 8; j++) a[ks][j] = (short)f2bf(sv[ks][j] * inv);

        // ---- PV: wave w owns E-cols eh*256 + [64w, 64w+64)
        const int EC = eh * 256 + w * 64;
        int tkc[5];
#pragma unroll
        for (int ks = 0; ks < 5; ks++) {
            int tok0 = R0 + ks * 32 + fq * 8;
            tkc[ks] = min(max(tok0, 0), L_SEQ - 8);
        }
        floatx4 oa[4] = {};
#pragma unroll
        for (int et = 0; et < 4; et++) {
            const unsigned short* vrow = vt + (size_t)(EC + et * 16 + fr) * 4096 + b * L_SEQ;
            short8 vfr[5];
#pragma unroll
            for (int ks = 0; ks < 5; ks++) vfr[ks] = *(const short8*)(vrow + tkc[ks]);
#pragma unroll
            for (int ks = 0; ks < 5; ks++)
                oa[et] = __builtin_amdgcn_mfma_f32_16x16x32_bf16(a[ks], vfr[ks], oa[et], 0, 0, 0);
        }

        float* op = out + (size_t)b * L_SEQ * E_DIM;
#pragma unroll
        for (int et = 0; et < 4; et++)
#pragma unroll
            for (int r = 0; r < 4; r++)
                op[(size_t)(Q0 + fq * 4 + r) * 512 + EC + et * 16 + fr] = oa[et][r];
    }
}

// ---------------- launch ----------------
extern "C" void kernel_launch(void* const* d_in, const int* in_sizes, int n_in,
                              void* d_out, int out_size, void* d_ws, size_t ws_size,
                              hipStream_t stream)
{
    const float* x  = (const float*)d_in[0];
    const float* Wq = (const float*)d_in[1];
    const float* bq = (const float*)d_in[2];
    const float* Wk = (const float*)d_in[3];
    const float* bk = (const float*)d_in[4];
    const float* Wv = (const float*)d_in[5];
    const float* bv = (const float*)d_in[6];
    float* out = (float*)d_out;

    char* ws = (char*)d_ws;
    unsigned short* qb = (unsigned short*)(ws);                  // 4 MB bf16 q
    unsigned short* kb = (unsigned short*)(ws + 4194304);        // 4 MB bf16 k
    unsigned short* vt = (unsigned short*)(ws + 8388608);        // 4 MB bf16 v^T [e][tok]
    unsigned short* xb = (unsigned short*)(ws + 12582912);       // 4 MB bf16 x
    unsigned short* wb = (unsigned short*)(ws + 16777216);       // 1.5 MB bf16 W
    unsigned int*  cnt = (unsigned int*)(ws + 33554432);         // barrier counter

    hipMemsetAsync(cnt, 0, 64, stream);                          // capturable memset node
    mega<<<NBLK, NTHR, 0, stream>>>(x, Wq, bq, Wk, bk, Wv, bv, out,
                                    xb, wb, qb, kb, vt, cnt);
}

// Round 11
// 118.822 us; speedup vs baseline: 1.8733x; 1.8733x over previous
//
#include <hip/hip_runtime.h>
#include <cstdint>
#include <cstddef>

#define L_SEQ 2048
#define E_DIM 512
#define WIN 64
#define SCALE_QK 0.044194173824159216f  // 1/sqrt(512)

typedef __attribute__((ext_vector_type(8))) short short8;
typedef __attribute__((ext_vector_type(4))) float floatx4;

__device__ __forceinline__ unsigned short f2bf(float f) {
    unsigned int u = __float_as_uint(f);
    u += 0x7FFFu + ((u >> 16) & 1u);
    return (unsigned short)(u >> 16);
}

// ---------------- fp32 -> bf16 conversion of x, Wq, Wk, Wv (R0, proven) -----
__global__ __launch_bounds__(256) void cvt_kernel(
    const float* __restrict__ x, const float* __restrict__ wq,
    const float* __restrict__ wk, const float* __restrict__ wv,
    unsigned short* __restrict__ xb, unsigned short* __restrict__ wb)
{
    long i = (long)blockIdx.x * 256 + threadIdx.x;   // 0 .. 720895
    const float* src;
    unsigned short* dst;
    long off;
    if (i < 524288) {
        src = x; dst = xb; off = i;
    } else {
        long j = i - 524288;
        int w = (int)(j >> 16);
        off = j & 65535;
        src = (w == 0) ? wq : ((w == 1) ? wk : wv);
        dst = wb + (long)w * 262144;
    }
    float4 f = ((const float4*)src)[off];
    ushort4 o;
    o.x = f2bf(f.x); o.y = f2bf(f.y); o.z = f2bf(f.z); o.w = f2bf(f.w);
    ((ushort4*)dst)[off] = o;
}

// ---------------- QKV projection: z-loop bf16 (R9/R10 phase B, proven) ------
// 512 blocks = (64 mt, 8 nt), bid%8 = mt%8 -> each XCD owns an m-stripe.
// Per kt: stage A once + all 3 B's, one barrier, A-frags reused across z.
#define ALD 72
__global__ __launch_bounds__(256, 2) void qkv_zloop(
    const unsigned short* __restrict__ xb, const unsigned short* __restrict__ wb,
    const float* __restrict__ bq, const float* __restrict__ bk, const float* __restrict__ bv,
    unsigned short* __restrict__ q, unsigned short* __restrict__ k,
    unsigned short* __restrict__ vt)
{
    __shared__ __align__(16) unsigned short As[64 * ALD];
    __shared__ __align__(16) unsigned short Bs[3][64 * ALD];

    const int t = threadIdx.x;
    const int bid = blockIdx.x;
    const int mt = bid & 63, nt = bid >> 6;
    const int m0 = mt * 64, n0 = nt * 64;

    const int w = t >> 6, l = t & 63;
    const int wm = (w >> 1) * 32, wn = (w & 1) * 32;
    const int fr = l & 15, fq = l >> 4, fk = fq * 8;

    const int srow = t >> 2, scol = (t & 3) * 16;
    const unsigned short* gA = xb + (size_t)(m0 + srow) * 512 + scol;
    const unsigned short* gB = wb + (size_t)(n0 + srow) * 512 + scol;

    float bv_[3][2];
    {
        const float* bs[3] = { bq, bk, bv };
#pragma unroll
        for (int z = 0; z < 3; z++)
#pragma unroll
            for (int j = 0; j < 2; j++) bv_[z][j] = bs[z][n0 + wn + j * 16 + fr];
    }

    floatx4 acc[3][2][2] = {};

    for (int kt = 0; kt < 8; kt++) {
        const int kk = kt * 64;
        *(uint4*)&As[srow * ALD + scol]     = *(const uint4*)(gA + kk);
        *(uint4*)&As[srow * ALD + scol + 8] = *(const uint4*)(gA + kk + 8);
#pragma unroll
        for (int z = 0; z < 3; z++) {
            *(uint4*)&Bs[z][srow * ALD + scol]     = *(const uint4*)(gB + (size_t)z * 262144 + kk);
            *(uint4*)&Bs[z][srow * ALD + scol + 8] = *(const uint4*)(gB + (size_t)z * 262144 + kk + 8);
        }
        __syncthreads();

        short8 a[2][2];
#pragma unroll
        for (int i = 0; i < 2; i++)
#pragma unroll
            for (int kh = 0; kh < 2; kh++)
                a[i][kh] = *(const short8*)&As[(wm + i * 16 + fr) * ALD + kh * 32 + fk];
#pragma unroll
        for (int z = 0; z < 3; z++) {
            short8 bf[2][2];
#pragma unroll
            for (int j = 0; j < 2; j++)
#pragma unroll
                for (int kh = 0; kh < 2; kh++)
                    bf[j][kh] = *(const short8*)&Bs[z][(wn + j * 16 + fr) * ALD + kh * 32 + fk];
#pragma unroll
            for (int kh = 0; kh < 2; kh++)
#pragma unroll
                for (int i = 0; i < 2; i++)
#pragma unroll
                    for (int j = 0; j < 2; j++)
                        acc[z][i][j] = __builtin_amdgcn_mfma_f32_16x16x32_bf16(a[i][kh], bf[j][kh], acc[z][i][j], 0, 0, 0);
        }
        __syncthreads();
    }

    // epilogue per z through LDS transpose tile (alias As)
    unsigned short* Tl = As;
    const int tr = t >> 2, tc = (t & 3) * 16;
#pragma unroll
    for (int z = 0; z < 3; z++) {
        if (z) __syncthreads();
        if (z < 2) {
#pragma unroll
            for (int i = 0; i < 2; i++)
#pragma unroll
                for (int j = 0; j < 2; j++)
#pragma unroll
                    for (int r = 0; r < 4; r++)
                        Tl[(wm + i * 16 + fq * 4 + r) * ALD + wn + j * 16 + fr] =
                            f2bf(acc[z][i][j][r] + bv_[z][j]);
        } else {
#pragma unroll
            for (int i = 0; i < 2; i++)
#pragma unroll
                for (int j = 0; j < 2; j++)
#pragma unroll
                    for (int r = 0; r < 4; r++)
                        Tl[(wn + j * 16 + fr) * ALD + wm + i * 16 + fq * 4 + r] =
                            f2bf(acc[z][i][j][r] + bv_[z][j]);
        }
        __syncthreads();

        uint4 v0 = *(const uint4*)&Tl[tr * ALD + tc];
        uint4 v1 = *(const uint4*)&Tl[tr * ALD + tc + 8];
        if (z < 2) {
            unsigned short* o = (z == 0) ? q : k;
            size_t off = (size_t)(m0 + tr) * 512 + n0 + tc;
            *(uint4*)&o[off]     = v0;
            *(uint4*)&o[off + 8] = v1;
        } else {
            size_t off = (size_t)(n0 + tr) * 4096 + m0 + tc;
            *(uint4*)&vt[off]     = v0;
            *(uint4*)&vt[off + 8] = v1;
        }
    }
}

// ---------------- fused attention: 8 waves, E-half split for 2 blocks/CU ----
// grid (128, 2 b, 2 eh), 512 threads, __launch_bounds__(512,4) => 2 blocks/CU
// = 16 waves/CU (2x the R3 TLP; attn is latency-bound: R1 profile MfmaUtil<1%).
// Scores computed redundantly per eh (latency-bound => cheap); wave w owns
// E-cols eh*256 + [32w, 32w+32).  Qt XCD-chunk-swizzled (R7-verified).
#define SLD 164
__global__ __launch_bounds__(512, 4) void attn_fused(
    const unsigned short* __restrict__ qb, const unsigned short* __restrict__ kb,
    const unsigned short* __restrict__ vt, float* __restrict__ out)
{
    __shared__ __align__(16) float Sl[16 * SLD];   // 10.5 KB (x2 blocks = 21 KB/CU)

    const int t = threadIdx.x;
    const int w = t >> 6, l = t & 63;
    const int fr = l & 15, fq = l >> 4;
    const int bx = blockIdx.x;
    const int Qt = (bx & 7) * 16 + (bx >> 3);      // XCD chunk-swizzle, bijective 0..127
    const int Q0 = Qt * 16;
    const int b  = blockIdx.y;
    const int eh = blockIdx.z;
    const int R0 = Q0 - WIN;

    // ---- scores: wave w handles n-tile(s) {w, w+8} (wave 0 gets two)
    {
        const unsigned short* qrow = qb + (size_t)(b * L_SEQ + Q0 + fr) * 512 + fq * 8;
        short8 qf[16];
#pragma unroll
        for (int ks = 0; ks < 16; ks++) qf[ks] = *(const short8*)(qrow + ks * 32);

        for (int nt = w; nt < 9; nt += 8) {
            const int tok = R0 + nt * 16 + fr;
            const bool kvalid = (tok >= 0) && (tok < L_SEQ);
            const int tokc = min(max(tok, 0), L_SEQ - 1);
            const unsigned short* krow = kb + (size_t)(b * L_SEQ + tokc) * 512 + fq * 8;

            floatx4 acc0 = {}, acc1 = {};
            short8 bfr[8];
#pragma unroll
            for (int ks = 0; ks < 8; ks++) bfr[ks] = *(const short8*)(krow + ks * 32);
#pragma unroll
            for (int ks = 0; ks < 8; ks++)
                acc0 = __builtin_amdgcn_mfma_f32_16x16x32_bf16(qf[ks], bfr[ks], acc0, 0, 0, 0);
#pragma unroll
            for (int ks = 0; ks < 8; ks++) bfr[ks] = *(const short8*)(krow + (8 + ks) * 32);
#pragma unroll
            for (int ks = 0; ks < 8; ks++)
                acc1 = __builtin_amdgcn_mfma_f32_16x16x32_bf16(qf[8 + ks], bfr[ks], acc1, 0, 0, 0);

            const int jg = nt * 16 + fr;
#pragma unroll
            for (int r = 0; r < 4; r++) {
                int qq = fq * 4 + r;    // C/D layout: col=lane&15, row=(lane>>4)*4+r
                bool valid = kvalid && (jg >= qq) && (jg <= qq + 128);
                Sl[qq * SLD + jg] = valid ? (acc0[r] + acc1[r]) * SCALE_QK : -1e30f;
            }
        }
    }
    __syncthreads();

    // ---- softmax (per-wave redundant): lane covers row fr, cols fq*8 + ks*32 + j
    const float* Srow = &Sl[fr * SLD + fq * 8];
    float sv[5][8];
#pragma unroll
    for (int ks = 0; ks < 5; ks++) {
        float4 u0 = *(const float4*)(Srow + ks * 32);
        float4 u1 = *(const float4*)(Srow + ks * 32 + 4);
        sv[ks][0] = u0.x; sv[ks][1] = u0.y; sv[ks][2] = u0.z; sv[ks][3] = u0.w;
        sv[ks][4] = u1.x; sv[ks][5] = u1.y; sv[ks][6] = u1.z; sv[ks][7] = u1.w;
    }
    if (fq >= 2) {                    // cols 144..159: unwritten pad
#pragma unroll
        for (int j = 0; j < 8; j++) sv[4][j] = -1e30f;
    }
    float m = -1e30f;
#pragma unroll
    for (int ks = 0; ks < 5; ks++)
#pragma unroll
        for (int j = 0; j < 8; j++) m = fmaxf(m, sv[ks][j]);
    m = fmaxf(m, __shfl_xor(m, 16));
    m = fmaxf(m, __shfl_xor(m, 32));
    float sum = 0.f;
#pragma unroll
    for (int ks = 0; ks < 5; ks++)
#pragma unroll
        for (int j = 0; j < 8; j++) { float e = __expf(sv[ks][j] - m); sv[ks][j] = e; sum += e; }
    sum += __shfl_xor(sum, 16);
    sum += __shfl_xor(sum, 32);
    float inv = 1.f / sum;

    short8 a[5];     // P in A-frag layout
#pragma unroll
    for (int ks = 0; ks < 5; ks++)
#pragma unroll
        for (int j = 0; j < 8; j++) a[ks][j] = (short)f2bf(sv[ks][j] * inv);

    // ---- PV: wave w owns E-cols eh*256 + [32w, 32w+32)
    const int EC = eh * 256 + w * 32;
    int tkc[5];
#pragma unroll
    for (int ks = 0; ks < 5; ks++) {
        int tok0 = R0 + ks * 32 + fq * 8;
        tkc[ks] = min(max(tok0, 0), L_SEQ - 8);
    }
    floatx4 oa[2] = {};
#pragma unroll
    for (int et = 0; et < 2; et++) {
        const unsigned short* vrow = vt + (size_t)(EC + et * 16 + fr) * 4096 + b * L_SEQ;
        short8 vfr[5];
#pragma unroll
        for (int ks = 0; ks < 5; ks++) vfr[ks] = *(const short8*)(vrow + tkc[ks]);
#pragma unroll
        for (int ks = 0; ks < 5; ks++)
            oa[et] = __builtin_amdgcn_mfma_f32_16x16x32_bf16(a[ks], vfr[ks], oa[et], 0, 0, 0);
    }

    float* op = out + (size_t)b * L_SEQ * E_DIM;
#pragma unroll
    for (int et = 0; et < 2; et++)
#pragma unroll
        for (int r = 0; r < 4; r++)
            op[(size_t)(Q0 + fq * 4 + r) * 512 + EC + et * 16 + fr] = oa[et][r];
}

// ---------------- launch ----------------
extern "C" void kernel_launch(void* const* d_in, const int* in_sizes, int n_in,
                              void* d_out, int out_size, void* d_ws, size_t ws_size,
                              hipStream_t stream)
{
    const float* x  = (const float*)d_in[0];
    const float* Wq = (const float*)d_in[1];
    const float* bq = (const float*)d_in[2];
    const float* Wk = (const float*)d_in[3];
    const float* bk = (const float*)d_in[4];
    const float* Wv = (const float*)d_in[5];
    const float* bv = (const float*)d_in[6];
    float* out = (float*)d_out;

    char* ws = (char*)d_ws;
    unsigned short* qb = (unsigned short*)(ws);                  // 4 MB bf16 q
    unsigned short* kb = (unsigned short*)(ws + 4194304);        // 4 MB bf16 k
    unsigned short* vt = (unsigned short*)(ws + 8388608);        // 4 MB bf16 v^T [e][tok]
    unsigned short* xb = (unsigned short*)(ws + 12582912);       // 4 MB bf16 x
    unsigned short* wb = (unsigned short*)(ws + 16777216);       // 1.5 MB bf16 W

    cvt_kernel<<<2816, 256, 0, stream>>>(x, Wq, Wk, Wv, xb, wb);
    qkv_zloop<<<512, 256, 0, stream>>>(xb, wb, bq, bk, bv, qb, kb, vt);
    attn_fused<<<dim3(128, 2, 2), 512, 0, stream>>>(qb, kb, vt, out);
}